// Round 1
// baseline (172.678 us; speedup 1.0000x reference)
//
#include <hip/hip_runtime.h>

// FwFM second-order interaction: out[b,d] = sum_{k<l} 0.5*(W[k,l]+W[l,k]) * x[k,b,d]*x[l,b,d]
// Identity used: v^T S v == v^T W v for S = 0.5(W+W^T), and diag(S) = diag(W),
// so out = 0.5 * sum_{k != l} W[k,l] v_k v_l  (741 unique pairs, K=39).
//
// Shapes fixed by the harness: x [39, 8192, 64] f32, W [39,39] f32, out [8192,64] f32.
// Memory-bound: 84 MB traffic -> ~13.3 us floor at 6.3 TB/s.

#define KF 39
#define NELEM (8192 * 64)   // B*D = 524288 output elements
#define NV2   (NELEM / 2)   // float2 elements per field = 262144

__global__ __launch_bounds__(256, 4) void fwfm_kernel(
    const float* __restrict__ x,
    const float* __restrict__ W,
    float* __restrict__ out) {
    const int n = blockIdx.x * 256 + threadIdx.x;   // float2 index in [0, NV2)

    const float2* __restrict__ x2 = reinterpret_cast<const float2*>(x);

    // Load this element-pair's 39-vector. Stride between fields is NV2 float2s.
    // Consecutive lanes -> consecutive addresses: fully coalesced dwordx2.
    float2 v[KF];
#pragma unroll
    for (int k = 0; k < KF; ++k) {
        v[k] = x2[(size_t)k * NV2 + n];
    }

    // Pairwise sum. Coefficient c is wave-uniform: compile-time indices on a
    // uniform pointer -> s_load + s_add on the scalar pipe; v_fma uses it as
    // the single SGPR operand. Two independent chains (x,y) for ILP.
    float accx = 0.0f, accy = 0.0f;
#pragma unroll
    for (int k = 1; k < KF; ++k) {
        float wx = 0.0f, wy = 0.0f;
#pragma unroll
        for (int l = 0; l < k; ++l) {
            const float c = W[k * KF + l] + W[l * KF + k];
            wx = fmaf(c, v[l].x, wx);
            wy = fmaf(c, v[l].y, wy);
        }
        accx = fmaf(v[k].x, wx, accx);
        accy = fmaf(v[k].y, wy, accy);
    }

    float2 o;
    o.x = 0.5f * accx;
    o.y = 0.5f * accy;
    reinterpret_cast<float2*>(out)[n] = o;
}

extern "C" void kernel_launch(void* const* d_in, const int* in_sizes, int n_in,
                              void* d_out, int out_size, void* d_ws, size_t ws_size,
                              hipStream_t stream) {
    const float* x = (const float*)d_in[0];          // [39, 8192, 64]
    const float* W = (const float*)d_in[1];          // [39, 39]
    float* out = (float*)d_out;                      // [8192, 64]

    fwfm_kernel<<<NV2 / 256, 256, 0, stream>>>(x, W, out);
}

// Round 2
// 119.175 us; speedup vs baseline: 1.4489x; 1.4489x over previous
//
#include <hip/hip_runtime.h>

// FwFM second-order interaction.
// Identity: v^T S v == v^T W v for S = 0.5(W+W^T), diag(S) = diag(W), so
//   out[b,d] = sum_{k<l} 0.5*(W[k,l]+W[l,k]) * x[k,b,d]*x[l,b,d]   (741 pairs, K=39)
//
// Shapes: x [39, 8192, 64] f32, W [39,39] f32, out [8192,64] f32.
// Memory-bound: ~84 MB traffic -> ~13.3 us floor at 6.3 TB/s achievable.
//
// R2 changes vs R1 (84 us, spilled):
//  - amdgpu_waves_per_eu(4,5): RA budget >= 102 VGPR so the 78-reg v[] array
//    stays resident (R1: RA chased 8 waves/EU -> 64 VGPR -> ~11 MB scratch spill).
//  - coefficients pre-symmetrized into d_ws contiguous in pair order ->
//    main kernel's uniform reads batch into s_load_dwordx16 (R1: 780 scattered
//    s_loads + 390 s_adds per wave saturated the scalar pipe).

#define KF 39
#define NPAIR (KF * (KF - 1) / 2)   // 741
#define NELEM (8192 * 64)           // B*D = 524288 output elements
#define NV2   (NELEM / 2)           // float2 elements per field = 262144

// Tiny precompute: c[p] = 0.5*(W[k,l]+W[l,k]) for l<k, p = k(k-1)/2 + l.
__global__ void fwfm_coef_kernel(const float* __restrict__ W, float* __restrict__ c) {
    const int t = blockIdx.x * 256 + threadIdx.x;   // over K*K = 1521
    if (t >= KF * KF) return;
    const int k = t / KF;
    const int l = t - k * KF;
    if (l < k) {
        c[(k * (k - 1)) / 2 + l] = 0.5f * (W[k * KF + l] + W[l * KF + k]);
    }
}

__global__ __attribute__((amdgpu_flat_work_group_size(256, 256), amdgpu_waves_per_eu(4, 5)))
void fwfm_kernel(const float* __restrict__ x,
                 const float* __restrict__ c,
                 float* __restrict__ out) {
    const int n = blockIdx.x * 256 + threadIdx.x;   // float2 index in [0, NV2)

    const float2* __restrict__ x2 = reinterpret_cast<const float2*>(x);

    // 39 coalesced dwordx2 loads; all can be outstanding before first use.
    float2 v[KF];
#pragma unroll
    for (int k = 0; k < KF; ++k) {
        v[k] = x2[(size_t)k * NV2 + n];
    }

    // Pair loop in coefficient order (p sequential -> batched s_loads).
    // c is wave-uniform: SGPR operand of v_fma; two chains (x,y) for ILP.
    float accx = 0.0f, accy = 0.0f;
    int p = 0;
#pragma unroll
    for (int k = 1; k < KF; ++k) {
        float wx = 0.0f, wy = 0.0f;
#pragma unroll
        for (int l = 0; l < k; ++l) {
            const float cc = c[p++];
            wx = fmaf(cc, v[l].x, wx);
            wy = fmaf(cc, v[l].y, wy);
        }
        accx = fmaf(v[k].x, wx, accx);
        accy = fmaf(v[k].y, wy, accy);
    }

    float2 o;
    o.x = accx;   // 0.5 already folded into c
    o.y = accy;
    reinterpret_cast<float2*>(out)[n] = o;
}

extern "C" void kernel_launch(void* const* d_in, const int* in_sizes, int n_in,
                              void* d_out, int out_size, void* d_ws, size_t ws_size,
                              hipStream_t stream) {
    const float* x = (const float*)d_in[0];          // [39, 8192, 64]
    const float* W = (const float*)d_in[1];          // [39, 39]
    float* out = (float*)d_out;                      // [8192, 64]
    float* coef = (float*)d_ws;                      // 741 floats of scratch

    fwfm_coef_kernel<<<(KF * KF + 255) / 256, 256, 0, stream>>>(W, coef);
    fwfm_kernel<<<NV2 / 256, 256, 0, stream>>>(x, coef, out);
}